// Round 13
// baseline (1585.165 us; speedup 1.0000x reference)
//
#include <hip/hip_runtime.h>
#include <math.h>

#define VOCAB 1000
#define EMB   128
#define HID   256
#define G4    1024   // 4*HID
#define BATCH 64
#define SEQT  1024
#define KVH   48     // reg h2 cols per k-half (12 chunks, cols 0-47)
#define KLS   8      // LDS h2 cols per k-half (2 chunks, cols 48-55)
#define KGH   8      // L2-global h2 cols per k-half (2 chunks, cols 56-63)
#define EPROJ_BLKS (VOCAB / 8)       // 125
#define PACK_BLKS  8                 // 8 blocks x 128 rows = 1024 rows

typedef unsigned int u32;
typedef _Float16 f16;
typedef __attribute__((ext_vector_type(2))) _Float16 h2v;
union H2U { u32 u; h2v h; unsigned short s[2]; };

#if defined(__has_builtin)
# if __has_builtin(__builtin_amdgcn_fdot2)
#  define HAVE_FDOT2 1
# endif
#endif
__device__ __forceinline__ float fdot2_(u32 a, u32 b, float c) {
    H2U ua, ub; ua.u = a; ub.u = b;
#ifdef HAVE_FDOT2
    return __builtin_amdgcn_fdot2(ua.h, ub.h, c, false);   // v_dot2_f32_f16
#else
    return c + (float)ua.h.x * (float)ub.h.x + (float)ua.h.y * (float)ub.h.y;
#endif
}

// In-loop barrier WITHOUT the vmcnt(0)/expcnt(0) drain __syncthreads emits
// (m97: full drain before s_barrier). In-loop cross-thread data (gs4, h2_sh)
// is LDS-only -> lgkmcnt(0) + s_barrier is sufficient; in-flight VMEM
// (weight tail + eproj prefetch) stays in flight across the barrier and is
// waited on by the compiler's own targeted vmcnt(N) at first use.
// sched_barrier(0) fences stop hipcc reordering memory ops across it (#18).
__device__ __forceinline__ void barrier_lgkm_() {
    __builtin_amdgcn_sched_barrier(0);
    asm volatile("s_waitcnt lgkmcnt(0)" ::: "memory");
    __builtin_amdgcn_s_barrier();
    __builtin_amdgcn_sched_barrier(0);
}

__device__ __forceinline__ float sigmoidf_(float x) {
    return 1.f / (1.f + __expf(-x));
}
__device__ __forceinline__ float tanhf_(float x) {
    return 1.f - 2.f / (__expf(2.f * x) + 1.f);
}

// ---------------------------------------------------------------------------
// Kernel 1 (merged prep): blocks 0..124 compute eproj (8 vocab rows/block,
// R11's proven version -- identical per-output fp op order); blocks 125..132
// pack W_hh fp32 -> fp16 half2 into the 3-way split (identical math to the
// old pack_whh kernel). Merging saves one kernel-launch gap.
// ---------------------------------------------------------------------------
__global__ __launch_bounds__(1024) void prep_kernel(
    const float* __restrict__ emb, const float* __restrict__ W_ih,
    const float* __restrict__ b_ih, const float* __restrict__ b_hh,
    const float* __restrict__ Whh, float* __restrict__ eproj,
    u32* __restrict__ wvq, u32* __restrict__ wlq, u32* __restrict__ wgq)
{
    if (blockIdx.x < EPROJ_BLKS) {
        const int v0 = blockIdx.x * 8;           // 125 blocks x 8 = 1000
        const int g  = threadIdx.x;              // gate row 0..1023
        __shared__ __align__(16) float4 x_sh[8][EMB / 4];   // 8 emb rows
        if (g < 256) {
            const int r = g >> 5, cc = g & 31;
            x_sh[r][cc] = ((const float4*)(emb + (size_t)(v0 + r) * EMB))[cc];
        }
        __syncthreads();
        const float4* wrow = (const float4*)(W_ih + (size_t)g * EMB);
        float a0[8], a1[8], a2[8], a3[8];
#pragma unroll
        for (int r = 0; r < 8; r++) { a0[r] = a1[r] = a2[r] = a3[r] = 0.f; }
#pragma unroll 4
        for (int e4 = 0; e4 < EMB / 4; e4++) {
            float4 wv = wrow[e4];
#pragma unroll
            for (int r = 0; r < 8; r++) {
                float4 xv = x_sh[r][e4];
                a0[r] += wv.x * xv.x;
                a1[r] += wv.y * xv.y;
                a2[r] += wv.z * xv.z;
                a3[r] += wv.w * xv.w;
            }
        }
        const float bias = b_ih[g] + b_hh[g];
#pragma unroll
        for (int r = 0; r < 8; r++)
            eproj[(size_t)(v0 + r) * G4 + g] =
                (a0[r] + a1[r]) + (a2[r] + a3[r]) + bias;
    } else {
        // pack: 8 blocks x 1024 thr; thread -> row r, 16 cols each
        const int r = (blockIdx.x - EPROJ_BLKS) * 128 + (threadIdx.x >> 3);
        const int m0 = (threadIdx.x & 7) * 16;
#pragma unroll
        for (int kk = 0; kk < 16; kk++) {
            const int m = m0 + kk;               // h2 col 0..127
            H2U u;
            u.h.x = (f16)Whh[(size_t)r * HID + 2 * m];
            u.h.y = (f16)Whh[(size_t)r * HID + 2 * m + 1];
            const int j  = m >> 6;               // k-half
            const int mm = m & 63;
            if (mm < KVH) {
                const int chunk = j * (KVH / 4) + (mm >> 2);
                wvq[(size_t)chunk * (G4 * 4) + r * 4 + (mm & 3)] = u.u;
            } else if (mm < KVH + KLS) {
                const int t2 = mm - KVH;
                const int chunk = j * (KLS / 4) + (t2 >> 2);
                wlq[(size_t)chunk * (G4 * 4) + r * 4 + (t2 & 3)] = u.u;
            } else {
                const int t2 = mm - KVH - KLS;
                const int chunk = j * (KGH / 4) + (t2 >> 2);
                wgq[(size_t)chunk * (G4 * 4) + r * 4 + (t2 & 3)] = u.u;
            }
        }
    }
}

// one register chunk (16 dots)
#define REG_CHUNK(q) do {                                                   \
    uint4 h4 = hb4[(q)];                                                    \
    aI = fdot2_(wI[4*(q)+0], h4.x, aI); aF = fdot2_(wF[4*(q)+0], h4.x, aF); \
    aG = fdot2_(wG[4*(q)+0], h4.x, aG); aO = fdot2_(wO[4*(q)+0], h4.x, aO); \
    aI = fdot2_(wI[4*(q)+1], h4.y, aI); aF = fdot2_(wF[4*(q)+1], h4.y, aF); \
    aG = fdot2_(wG[4*(q)+1], h4.y, aG); aO = fdot2_(wO[4*(q)+1], h4.y, aO); \
    aI = fdot2_(wI[4*(q)+2], h4.z, aI); aF = fdot2_(wF[4*(q)+2], h4.z, aF); \
    aG = fdot2_(wG[4*(q)+2], h4.z, aG); aO = fdot2_(wO[4*(q)+2], h4.z, aO); \
    aI = fdot2_(wI[4*(q)+3], h4.w, aI); aF = fdot2_(wF[4*(q)+3], h4.w, aF); \
    aG = fdot2_(wG[4*(q)+3], h4.w, aG); aO = fdot2_(wO[4*(q)+3], h4.w, aO); \
} while (0)

// one in-register (pre-loaded) chunk: weights tI..tO vs h chunk hq
#define VAL_CHUNK(tI, tF, tG, tO, hq) do {                                  \
    uint4 h4 = hb4[(hq)];                                                   \
    aI = fdot2_((tI).x, h4.x, aI); aF = fdot2_((tF).x, h4.x, aF);           \
    aG = fdot2_((tG).x, h4.x, aG); aO = fdot2_((tO).x, h4.x, aO);           \
    aI = fdot2_((tI).y, h4.y, aI); aF = fdot2_((tF).y, h4.y, aF);           \
    aG = fdot2_((tG).y, h4.y, aG); aO = fdot2_((tO).y, h4.y, aO);           \
    aI = fdot2_((tI).z, h4.z, aI); aF = fdot2_((tF).z, h4.z, aF);           \
    aG = fdot2_((tG).z, h4.z, aG); aO = fdot2_((tO).z, h4.z, aO);           \
    aI = fdot2_((tI).w, h4.w, aI); aF = fdot2_((tF).w, h4.w, aF);           \
    aG = fdot2_((tG).w, h4.w, aG); aO = fdot2_((tO).w, h4.w, aO);           \
} while (0)

// ---------------------------------------------------------------------------
// Kernel 2: single-CU LSTM (R12 structure) with lgkmcnt-only in-loop
// barriers. R12's null (LDS 140K->75K, dur unchanged) + m97's finding that
// __syncthreads emits a FULL vmcnt(0) drain showed the per-step cost is the
// barrier drain of in-flight VMEM (12 loads: 8 weight-tail + 4 eproj
// prefetch), not LDS bandwidth. In-loop barriers only guard LDS data (gs4,
// h2_sh) -> lgkmcnt(0)+s_barrier suffices; VMEM stays in flight across
// barriers, waited by the compiler's targeted vmcnt(N) at first use.
// Everything else identical to R12 -> bit-identical numerics.
// ---------------------------------------------------------------------------
__global__ __launch_bounds__(512, 2) void lstm_single_cu(
    const int* __restrict__ ids, const int* __restrict__ lens,
    const float* __restrict__ eproj,
    const u32* __restrict__ wvq, const u32* __restrict__ wlq,
    const u32* __restrict__ wgq, float* __restrict__ out)
{
    const int b   = blockIdx.x;
    const int tau = threadIdx.x;                 // 0..511
    const int u   = tau & (HID - 1);             // unit
    const int j   = tau >> 8;                    // k-half (wave-uniform)
    const int rI  = u;                           // gate rows of unit u
    const int rF  = 256 + u;
    const int rG  = 512 + u;
    const int rO  = 768 + u;

    __shared__ u32    wl_sh[4 * G4 * 4];         // 4 chunks x 1024 x 16B = 64KB
    __shared__ u32    h2_sh[2][HID / 2];         // h as half2, parity x2
    __shared__ float4 gs4[HID];                  // j=1 partials bounce
    __shared__ int    id_sh[SEQT];               // id row (4 KB)

    const int* idr = ids + (size_t)b * SEQT;
    ((int2*)id_sh)[tau] = ((const int2*)idr)[tau];    // 512 x 8B
    if (tau < HID / 2) h2_sh[0][tau] = 0u;            // h(0) = 0

    // stage LDS weight tail (b128 both sides, coalesced): 8 iters, 64 KB
    {
        const uint4* src = (const uint4*)wlq;
        uint4*       dst = (uint4*)wl_sh;
#pragma unroll
        for (int t = 0; t < 4 * G4 / 512; t++)
            dst[t * 512 + tau] = src[t * 512 + tau];
    }

    // persistent weights: 4 gates x 48 h2 = 192 regs (VGPR+AGPR unified)
    u32 wI[KVH], wF[KVH], wG[KVH], wO[KVH];
#pragma unroll
    for (int q = 0; q < KVH / 4; q++) {
        const int ch = j * (KVH / 4) + q;
        uint4 ti = ((const uint4*)wvq)[ch * G4 + rI];
        uint4 tf = ((const uint4*)wvq)[ch * G4 + rF];
        uint4 tg = ((const uint4*)wvq)[ch * G4 + rG];
        uint4 to = ((const uint4*)wvq)[ch * G4 + rO];
        wI[4 * q + 0] = ti.x; wI[4 * q + 1] = ti.y;
        wI[4 * q + 2] = ti.z; wI[4 * q + 3] = ti.w;
        wF[4 * q + 0] = tf.x; wF[4 * q + 1] = tf.y;
        wF[4 * q + 2] = tf.z; wF[4 * q + 3] = tf.w;
        wG[4 * q + 0] = tg.x; wG[4 * q + 1] = tg.y;
        wG[4 * q + 2] = tg.z; wG[4 * q + 3] = tg.w;
        wO[4 * q + 0] = to.x; wO[4 * q + 1] = to.y;
        wO[4 * q + 2] = to.z; wO[4 * q + 3] = to.w;
    }

    // loop-invariant global-tail bases (2 chunks for this thread's k-half)
    const uint4* g0 = (const uint4*)wgq + (size_t)(2 * j + 0) * G4;
    const uint4* g1 = (const uint4*)wgq + (size_t)(2 * j + 1) * G4;

    const int len = lens[b];                     // >= 1
    float c = 0.f, hf = 0.f;

    // x projections live in the j=0 accumulators only
    float xI = 0.f, xF = 0.f, xG = 0.f, xO = 0.f;
    if (j == 0) {
        const float* e0 = eproj + (size_t)idr[0] * G4;
        xI = e0[rI]; xF = e0[rF]; xG = e0[rG]; xO = e0[rO];
    }

    // prologue: issue the first global-tail loads (consumed at step-0 top)
    uint4 gi0 = g0[rI], gf0 = g0[rF], gg0 = g0[rG], go0 = g0[rO];
    uint4 gi1 = g1[rI], gf1 = g1[rF], gg1 = g1[rG], go1 = g1[rO];

    __syncthreads();                             // full barrier once (staging)

    for (int t = 0; t < len; t++) {
        // prefetch next step's input projections (j=0 only, wave-uniform)
        const int nt = (t + 1 < len) ? t + 1 : len - 1;
        const int nid = id_sh[nt];
        float nI = 0.f, nF = 0.f, nG = 0.f, nO = 0.f;
        if (j == 0) {
            const float* en = eproj + (size_t)nid * G4;
            nI = en[rI]; nF = en[rF]; nG = en[rG]; nO = en[rO];
        }

        const int p = t & 1;
        const uint4* hb4 = (const uint4*)h2_sh[p] + 16 * j;  // this k-half
        float aI = xI, aF = xF, aG = xG, aO = xO;

        // global tail (cols 56-63): consume the in-flight loads first,
        // so the buffers are dead before the reg-dot region begins
        VAL_CHUNK(gi0, gf0, gg0, go0, 14);
        VAL_CHUNK(gi1, gf1, gg1, go1, 15);

        // register cols 0..47 (12 chunks)
#pragma unroll
        for (int q = 0; q < KVH / 4; q++) REG_CHUNK(q);

        // LDS tail (cols 48-55, 2 chunks; lane-consecutive b128)
#pragma unroll
        for (int q = 0; q < KLS / 4; q++) {
            const int ch = j * (KLS / 4) + q;
            uint4 tI = ((const uint4*)wl_sh)[ch * G4 + rI];
            uint4 tF = ((const uint4*)wl_sh)[ch * G4 + rF];
            uint4 tG = ((const uint4*)wl_sh)[ch * G4 + rG];
            uint4 tO = ((const uint4*)wl_sh)[ch * G4 + rO];
            VAL_CHUNK(tI, tF, tG, tO, KVH / 4 + q);
        }

        // issue next step's global-tail loads: loop-invariant addresses,
        // L2-hot; now genuinely in flight across the (lgkm-only) barriers.
        gi0 = g0[rI]; gf0 = g0[rF]; gg0 = g0[rG]; go0 = g0[rO];
        gi1 = g1[rI]; gf1 = g1[rF]; gg1 = g1[rG]; go1 = g1[rO];

        if (j == 1) {                // publish raw k-half-1 partials (b128)
            gs4[u] = make_float4(aI, aF, aG, aO);
        }
        barrier_lgkm_();             // barrier A: partials visible (LDS only)

        if (j == 0) {                // combine + activate + state update
            float4 pp = gs4[u];
            float ig = sigmoidf_(aI + pp.x);
            float fg = sigmoidf_(aF + pp.y);
            float gg2 = tanhf_(aG + pp.z);
            float og = sigmoidf_(aO + pp.w);
            c  = fg * c + ig * gg2;
            hf = og * tanhf_(c);
            H2U hv; hv.h.x = (f16)hf; hv.h.y = (f16)0.f;
            ((unsigned short*)h2_sh[p ^ 1])[u] = hv.s[0];
        }
        xI = nI; xF = nF; xG = nG; xO = nO;
        barrier_lgkm_();             // barrier B: h(t+1) published (LDS only)
    }

    if (tau < HID) out[(size_t)b * HID + u] = hf;   // j=0 threads hold state
}

// ---------------------------------------------------------------------------
// Fallback (ws too small): correct-but-slow single-block fp32 version.
// ---------------------------------------------------------------------------
__global__ __launch_bounds__(1024, 1) void lstm_fallback(
    const int* __restrict__ ids, const int* __restrict__ lens,
    const float* __restrict__ emb, const float* __restrict__ W_ih,
    const float* __restrict__ b_ih, const float* __restrict__ b_hh,
    const float* __restrict__ W_hh, float* __restrict__ out)
{
    const int b = blockIdx.x;
    const int t = threadIdx.x;

    __shared__ __align__(16) float h_sh[HID];
    __shared__ __align__(16) float c_sh[HID];
    __shared__ __align__(16) float gates[G4];
    __shared__ __align__(16) float x_sh[EMB];

    float wih[EMB];
    {
        const float4* wr = (const float4*)(W_ih + (size_t)t * EMB);
#pragma unroll
        for (int e4 = 0; e4 < EMB / 4; e4++) {
            float4 wv = wr[e4];
            wih[4 * e4 + 0] = wv.x;
            wih[4 * e4 + 1] = wv.y;
            wih[4 * e4 + 2] = wv.z;
            wih[4 * e4 + 3] = wv.w;
        }
    }
    float bias = b_ih[t] + b_hh[t];

    const int len = lens[b];
    const int* ids_row = ids + (size_t)b * SEQT;
    if (t < HID) { h_sh[t] = 0.f; c_sh[t] = 0.f; }
    __syncthreads();

    for (int step = 0; step < len; step++) {
        int id = ids_row[step];
        if (t < EMB / 4) {
            ((float4*)x_sh)[t] = ((const float4*)(emb + (size_t)id * EMB))[t];
        }
        __syncthreads();
        float a0 = bias, a1 = 0.f, a2 = 0.f, a3 = 0.f;
#pragma unroll
        for (int e4 = 0; e4 < EMB / 4; e4++) {
            float4 xv = ((const float4*)x_sh)[e4];
            a0 += wih[4 * e4 + 0] * xv.x;
            a1 += wih[4 * e4 + 1] * xv.y;
            a2 += wih[4 * e4 + 2] * xv.z;
            a3 += wih[4 * e4 + 3] * xv.w;
        }
        float acc = (a0 + a1) + (a2 + a3);

        const float* wrow = W_hh + (size_t)t * HID;
        a0 = acc; a1 = 0.f; a2 = 0.f; a3 = 0.f;
        for (int k4 = 0; k4 < HID / 4; k4++) {
            float4 hv = ((const float4*)h_sh)[k4];
            float4 wv = ((const float4*)wrow)[k4];
            a0 += wv.x * hv.x;
            a1 += wv.y * hv.y;
            a2 += wv.z * hv.z;
            a3 += wv.w * hv.w;
        }
        gates[t] = (a0 + a1) + (a2 + a3);
        __syncthreads();

        if (t < HID) {
            float ig = sigmoidf_(gates[t]);
            float fg = sigmoidf_(gates[HID + t]);
            float gg = tanhf_(gates[2 * HID + t]);
            float og = sigmoidf_(gates[3 * HID + t]);
            float cc = fg * c_sh[t] + ig * gg;
            c_sh[t] = cc;
            h_sh[t] = og * tanhf_(cc);
        }
        __syncthreads();
    }
    if (t < HID) out[(size_t)b * HID + t] = h_sh[t];
}

extern "C" void kernel_launch(void* const* d_in, const int* in_sizes, int n_in,
                              void* d_out, int out_size, void* d_ws, size_t ws_size,
                              hipStream_t stream) {
    const int*   ids  = (const int*)d_in[0];
    const int*   lens = (const int*)d_in[1];
    const float* emb  = (const float*)d_in[2];
    const float* Wih  = (const float*)d_in[3];
    const float* Whh  = (const float*)d_in[4];
    const float* bih  = (const float*)d_in[5];
    const float* bhh  = (const float*)d_in[6];
    float* out = (float*)d_out;

    // ws layout: eproj 4 MB | wvq 384 KB | wlq 64 KB | wgq 64 KB
    const size_t ep_bytes = (size_t)VOCAB * G4 * sizeof(float);
    const size_t wv_off   = ep_bytes;
    const size_t wv_bytes = (size_t)2 * (KVH / 4) * G4 * 4 * sizeof(u32);
    const size_t wl_off   = wv_off + wv_bytes;
    const size_t wl_bytes = (size_t)2 * (KLS / 4) * G4 * 4 * sizeof(u32);
    const size_t wg_off   = wl_off + wl_bytes;
    const size_t wg_bytes = (size_t)2 * (KGH / 4) * G4 * 4 * sizeof(u32);

    if (ws_size >= wg_off + wg_bytes) {
        float* eproj = (float*)d_ws;
        u32*   wvp   = (u32*)((char*)d_ws + wv_off);
        u32*   wlp   = (u32*)((char*)d_ws + wl_off);
        u32*   wgp   = (u32*)((char*)d_ws + wg_off);
        prep_kernel<<<EPROJ_BLKS + PACK_BLKS, 1024, 0, stream>>>(
            emb, Wih, bih, bhh, Whh, eproj, wvp, wlp, wgp);
        lstm_single_cu<<<BATCH, 512, 0, stream>>>(
            ids, lens, eproj, wvp, wlp, wgp, out);
    } else {
        lstm_fallback<<<BATCH, 1024, 0, stream>>>(
            ids, lens, emb, Wih, bih, bhh, Whh, out);
    }
}

// Round 14
// 1563.656 us; speedup vs baseline: 1.0138x; 1.0138x over previous
//
#include <hip/hip_runtime.h>
#include <math.h>

#define VOCAB 1000
#define EMB   128
#define HID   256
#define G4    1024   // 4*HID
#define BATCH 64
#define SEQT  1024
#define KVH   48     // reg h2 cols per k-half (12 chunks, cols 0-47)
#define KLS   8      // LDS h2 cols per k-half (2 chunks, cols 48-55)
#define KGH   8      // L2-global h2 cols per k-half (2 chunks, cols 56-63)

typedef unsigned int u32;
typedef _Float16 f16;
typedef __attribute__((ext_vector_type(2))) _Float16 h2v;
union H2U { u32 u; h2v h; unsigned short s[2]; };

#if defined(__has_builtin)
# if __has_builtin(__builtin_amdgcn_fdot2)
#  define HAVE_FDOT2 1
# endif
#endif
__device__ __forceinline__ float fdot2_(u32 a, u32 b, float c) {
    H2U ua, ub; ua.u = a; ub.u = b;
#ifdef HAVE_FDOT2
    return __builtin_amdgcn_fdot2(ua.h, ub.h, c, false);   // v_dot2_f32_f16
#else
    return c + (float)ua.h.x * (float)ub.h.x + (float)ua.h.y * (float)ub.h.y;
#endif
}

__device__ __forceinline__ float sigmoidf_(float x) {
    return 1.f / (1.f + __expf(-x));
}
__device__ __forceinline__ float tanhf_(float x) {
    return 1.f - 2.f / (__expf(2.f * x) + 1.f);
}

// ---------------------------------------------------------------------------
// Kernel 1: eproj[v][g] = emb[v] . W_ih[g] + b_ih[g] + b_hh[g]   (fp32, exact)
// 8 vocab rows per block: W_ih streamed once per 8 outputs (R11's proven
// version, L2 W_ih traffic 512 MB -> 64 MB). Per-output fp op order
// byte-identical to the original.
// ---------------------------------------------------------------------------
__global__ __launch_bounds__(1024) void eproj_kernel(
    const float* __restrict__ emb, const float* __restrict__ W_ih,
    const float* __restrict__ b_ih, const float* __restrict__ b_hh,
    float* __restrict__ eproj)
{
    const int v0 = blockIdx.x * 8;               // 125 blocks x 8 = 1000
    const int g  = threadIdx.x;                  // gate row 0..1023
    __shared__ __align__(16) float4 x_sh[8][EMB / 4];   // 8 emb rows, 4 KB
    if (g < 256) {
        const int r = g >> 5, cc = g & 31;
        x_sh[r][cc] = ((const float4*)(emb + (size_t)(v0 + r) * EMB))[cc];
    }
    __syncthreads();
    const float4* wrow = (const float4*)(W_ih + (size_t)g * EMB);
    float a0[8], a1[8], a2[8], a3[8];
#pragma unroll
    for (int r = 0; r < 8; r++) { a0[r] = a1[r] = a2[r] = a3[r] = 0.f; }
#pragma unroll 4
    for (int e4 = 0; e4 < EMB / 4; e4++) {
        float4 wv = wrow[e4];
#pragma unroll
        for (int r = 0; r < 8; r++) {
            float4 xv = x_sh[r][e4];
            a0[r] += wv.x * xv.x;
            a1[r] += wv.y * xv.y;
            a2[r] += wv.z * xv.z;
            a3[r] += wv.w * xv.w;
        }
    }
    const float bias = b_ih[g] + b_hh[g];
#pragma unroll
    for (int r = 0; r < 8; r++)
        eproj[(size_t)(v0 + r) * G4 + g] =
            (a0[r] + a1[r]) + (a2[r] + a3[r]) + bias;
}

// ---------------------------------------------------------------------------
// Kernel 2: pack W_hh fp32 -> fp16 half2, 3-way k-half split layout.
// h2 col m (0..127): half j = m>>6, within-half col mm = m&63.
// mm <  48       -> wvq chunk j*12 + mm/4        (register part, 24 ch, 384 KB)
// 48 <= mm < 56  -> wlq chunk j*2 + (mm-48)/4    (LDS part, 4 ch, 64 KB)
// mm >= 56       -> wgq chunk j*2 + (mm-56)/4    (L2-global part, 4 ch, 64 KB)
// [chunk][row][4] keeps global loads and LDS b128 reads lane-consecutive.
// ---------------------------------------------------------------------------
__global__ __launch_bounds__(128) void pack_whh(
    const float* __restrict__ Whh, u32* __restrict__ wvq,
    u32* __restrict__ wlq, u32* __restrict__ wgq)
{
    const int r = blockIdx.x;        // row 0..1023
    const int m = threadIdx.x;       // h2 col 0..127
    H2U u;
    u.h.x = (f16)Whh[(size_t)r * HID + 2 * m];
    u.h.y = (f16)Whh[(size_t)r * HID + 2 * m + 1];
    const int j  = m >> 6;           // k-half
    const int mm = m & 63;
    if (mm < KVH) {
        const int chunk = j * (KVH / 4) + (mm >> 2);
        wvq[(size_t)chunk * (G4 * 4) + r * 4 + (mm & 3)] = u.u;
    } else if (mm < KVH + KLS) {
        const int t2 = mm - KVH;
        const int chunk = j * (KLS / 4) + (t2 >> 2);
        wlq[(size_t)chunk * (G4 * 4) + r * 4 + (t2 & 3)] = u.u;
    } else {
        const int t2 = mm - KVH - KLS;
        const int chunk = j * (KGH / 4) + (t2 >> 2);
        wgq[(size_t)chunk * (G4 * 4) + r * 4 + (t2 & 3)] = u.u;
    }
}

// one register chunk (16 dots)
#define REG_CHUNK(q) do {                                                   \
    uint4 h4 = hb4[(q)];                                                    \
    aI = fdot2_(wI[4*(q)+0], h4.x, aI); aF = fdot2_(wF[4*(q)+0], h4.x, aF); \
    aG = fdot2_(wG[4*(q)+0], h4.x, aG); aO = fdot2_(wO[4*(q)+0], h4.x, aO); \
    aI = fdot2_(wI[4*(q)+1], h4.y, aI); aF = fdot2_(wF[4*(q)+1], h4.y, aF); \
    aG = fdot2_(wG[4*(q)+1], h4.y, aG); aO = fdot2_(wO[4*(q)+1], h4.y, aO); \
    aI = fdot2_(wI[4*(q)+2], h4.z, aI); aF = fdot2_(wF[4*(q)+2], h4.z, aF); \
    aG = fdot2_(wG[4*(q)+2], h4.z, aG); aO = fdot2_(wO[4*(q)+2], h4.z, aO); \
    aI = fdot2_(wI[4*(q)+3], h4.w, aI); aF = fdot2_(wF[4*(q)+3], h4.w, aF); \
    aG = fdot2_(wG[4*(q)+3], h4.w, aG); aO = fdot2_(wO[4*(q)+3], h4.w, aO); \
} while (0)

// one in-register (pre-loaded) chunk: weights tI..tO vs h chunk hq
#define VAL_CHUNK(tI, tF, tG, tO, hq) do {                                  \
    uint4 h4 = hb4[(hq)];                                                   \
    aI = fdot2_((tI).x, h4.x, aI); aF = fdot2_((tF).x, h4.x, aF);           \
    aG = fdot2_((tG).x, h4.x, aG); aO = fdot2_((tO).x, h4.x, aO);           \
    aI = fdot2_((tI).y, h4.y, aI); aF = fdot2_((tF).y, h4.y, aF);           \
    aG = fdot2_((tG).y, h4.y, aG); aO = fdot2_((tO).y, h4.y, aO);           \
    aI = fdot2_((tI).z, h4.z, aI); aF = fdot2_((tF).z, h4.z, aF);           \
    aG = fdot2_((tG).z, h4.z, aG); aO = fdot2_((tO).z, h4.z, aO);           \
    aI = fdot2_((tI).w, h4.w, aI); aF = fdot2_((tF).w, h4.w, aF);           \
    aG = fdot2_((tG).w, h4.w, aG); aO = fdot2_((tO).w, h4.w, aO);           \
} while (0)

// ---------------------------------------------------------------------------
// Kernel 3: single-CU LSTM, cross-wave k-split — the best-measured
// configuration of this session (R12: dispatch 1490us, bench 1562us).
// Final structure after the full bracket:
//  - 512 thr, 2 waves/SIMD (occupancy bracket R0/R3/R5);
//  - k-split across waves: thread (u=tau&255, j=tau>>8) computes all 4
//    gates of unit u over k-half j -> 64-deep chains, 16 h-broadcasts +
//    8 lane-spread tail reads per thread (R7's +10% win);
//  - weight tail 3-way: 48 cols in VGPR/AGPR, 8 in LDS, 8 via L2 global
//    cross-step pipelined (R12; null vs LDS-only but frees LDS);
//  - gs4 LDS bounce + two __syncthreads per step (R8/R9/R10 exchange
//    bracket: LDS bounce beats bpermute and permlane variants; R13:
//    lgkm-only barriers are null-to-negative).
// Remaining time is the serial recurrence skeleton (all pipes <33% busy);
// 6 structural attacks (R8-R13) failed to compress it further.
// ---------------------------------------------------------------------------
__global__ __launch_bounds__(512, 2) void lstm_single_cu(
    const int* __restrict__ ids, const int* __restrict__ lens,
    const float* __restrict__ eproj,
    const u32* __restrict__ wvq, const u32* __restrict__ wlq,
    const u32* __restrict__ wgq, float* __restrict__ out)
{
    const int b   = blockIdx.x;
    const int tau = threadIdx.x;                 // 0..511
    const int u   = tau & (HID - 1);             // unit
    const int j   = tau >> 8;                    // k-half (wave-uniform)
    const int rI  = u;                           // gate rows of unit u
    const int rF  = 256 + u;
    const int rG  = 512 + u;
    const int rO  = 768 + u;

    __shared__ u32    wl_sh[4 * G4 * 4];         // 4 chunks x 1024 x 16B = 64KB
    __shared__ u32    h2_sh[2][HID / 2];         // h as half2, parity x2
    __shared__ float4 gs4[HID];                  // j=1 partials bounce
    __shared__ int    id_sh[SEQT];               // id row (4 KB)

    const int* idr = ids + (size_t)b * SEQT;
    ((int2*)id_sh)[tau] = ((const int2*)idr)[tau];    // 512 x 8B
    if (tau < HID / 2) h2_sh[0][tau] = 0u;            // h(0) = 0

    // stage LDS weight tail (b128 both sides, coalesced): 8 iters, 64 KB
    {
        const uint4* src = (const uint4*)wlq;
        uint4*       dst = (uint4*)wl_sh;
#pragma unroll
        for (int t = 0; t < 4 * G4 / 512; t++)
            dst[t * 512 + tau] = src[t * 512 + tau];
    }

    // persistent weights: 4 gates x 48 h2 = 192 regs (VGPR+AGPR unified)
    u32 wI[KVH], wF[KVH], wG[KVH], wO[KVH];
#pragma unroll
    for (int q = 0; q < KVH / 4; q++) {
        const int ch = j * (KVH / 4) + q;
        uint4 ti = ((const uint4*)wvq)[ch * G4 + rI];
        uint4 tf = ((const uint4*)wvq)[ch * G4 + rF];
        uint4 tg = ((const uint4*)wvq)[ch * G4 + rG];
        uint4 to = ((const uint4*)wvq)[ch * G4 + rO];
        wI[4 * q + 0] = ti.x; wI[4 * q + 1] = ti.y;
        wI[4 * q + 2] = ti.z; wI[4 * q + 3] = ti.w;
        wF[4 * q + 0] = tf.x; wF[4 * q + 1] = tf.y;
        wF[4 * q + 2] = tf.z; wF[4 * q + 3] = tf.w;
        wG[4 * q + 0] = tg.x; wG[4 * q + 1] = tg.y;
        wG[4 * q + 2] = tg.z; wG[4 * q + 3] = tg.w;
        wO[4 * q + 0] = to.x; wO[4 * q + 1] = to.y;
        wO[4 * q + 2] = to.z; wO[4 * q + 3] = to.w;
    }

    // loop-invariant global-tail bases (2 chunks for this thread's k-half)
    const uint4* g0 = (const uint4*)wgq + (size_t)(2 * j + 0) * G4;
    const uint4* g1 = (const uint4*)wgq + (size_t)(2 * j + 1) * G4;

    const int len = lens[b];                     // >= 1
    float c = 0.f, hf = 0.f;

    // x projections live in the j=0 accumulators only
    float xI = 0.f, xF = 0.f, xG = 0.f, xO = 0.f;
    if (j == 0) {
        const float* e0 = eproj + (size_t)idr[0] * G4;
        xI = e0[rI]; xF = e0[rF]; xG = e0[rG]; xO = e0[rO];
    }

    // prologue: issue the first global-tail loads (consumed at step-0 top)
    uint4 gi0 = g0[rI], gf0 = g0[rF], gg0 = g0[rG], go0 = g0[rO];
    uint4 gi1 = g1[rI], gf1 = g1[rF], gg1 = g1[rG], go1 = g1[rO];

    __syncthreads();

    for (int t = 0; t < len; t++) {
        // prefetch next step's input projections (j=0 only, wave-uniform)
        const int nt = (t + 1 < len) ? t + 1 : len - 1;
        const int nid = id_sh[nt];
        float nI = 0.f, nF = 0.f, nG = 0.f, nO = 0.f;
        if (j == 0) {
            const float* en = eproj + (size_t)nid * G4;
            nI = en[rI]; nF = en[rF]; nG = en[rG]; nO = en[rO];
        }

        const int p = t & 1;
        const uint4* hb4 = (const uint4*)h2_sh[p] + 16 * j;  // this k-half
        float aI = xI, aF = xF, aG = xG, aO = xO;

        // global tail (cols 56-63): consume the in-flight loads first,
        // so the buffers are dead before the reg-dot region begins
        VAL_CHUNK(gi0, gf0, gg0, go0, 14);
        VAL_CHUNK(gi1, gf1, gg1, go1, 15);

        // register cols 0..47 (12 chunks)
#pragma unroll
        for (int q = 0; q < KVH / 4; q++) REG_CHUNK(q);

        // LDS tail (cols 48-55, 2 chunks; lane-consecutive b128)
#pragma unroll
        for (int q = 0; q < KLS / 4; q++) {
            const int ch = j * (KLS / 4) + q;
            uint4 tI = ((const uint4*)wl_sh)[ch * G4 + rI];
            uint4 tF = ((const uint4*)wl_sh)[ch * G4 + rF];
            uint4 tG = ((const uint4*)wl_sh)[ch * G4 + rG];
            uint4 tO = ((const uint4*)wl_sh)[ch * G4 + rO];
            VAL_CHUNK(tI, tF, tG, tO, KVH / 4 + q);
        }

        // issue next step's global-tail loads (loop-invariant, L2-hot)
        gi0 = g0[rI]; gf0 = g0[rF]; gg0 = g0[rG]; go0 = g0[rO];
        gi1 = g1[rI]; gf1 = g1[rF]; gg1 = g1[rG]; go1 = g1[rO];

        if (j == 1) {                // publish raw k-half-1 partials (b128)
            gs4[u] = make_float4(aI, aF, aG, aO);
        }
        __syncthreads();             // barrier A: partials visible

        if (j == 0) {                // combine + activate + state update
            float4 pp = gs4[u];
            float ig = sigmoidf_(aI + pp.x);
            float fg = sigmoidf_(aF + pp.y);
            float gg2 = tanhf_(aG + pp.z);
            float og = sigmoidf_(aO + pp.w);
            c  = fg * c + ig * gg2;
            hf = og * tanhf_(c);
            H2U hv; hv.h.x = (f16)hf; hv.h.y = (f16)0.f;
            ((unsigned short*)h2_sh[p ^ 1])[u] = hv.s[0];
        }
        xI = nI; xF = nF; xG = nG; xO = nO;
        __syncthreads();             // barrier B: h(t+1) published
    }

    if (tau < HID) out[(size_t)b * HID + u] = hf;   // j=0 threads hold state
}

// ---------------------------------------------------------------------------
// Fallback (ws too small): correct-but-slow single-block fp32 version.
// ---------------------------------------------------------------------------
__global__ __launch_bounds__(1024, 1) void lstm_fallback(
    const int* __restrict__ ids, const int* __restrict__ lens,
    const float* __restrict__ emb, const float* __restrict__ W_ih,
    const float* __restrict__ b_ih, const float* __restrict__ b_hh,
    const float* __restrict__ W_hh, float* __restrict__ out)
{
    const int b = blockIdx.x;
    const int t = threadIdx.x;

    __shared__ __align__(16) float h_sh[HID];
    __shared__ __align__(16) float c_sh[HID];
    __shared__ __align__(16) float gates[G4];
    __shared__ __align__(16) float x_sh[EMB];

    float wih[EMB];
    {
        const float4* wr = (const float4*)(W_ih + (size_t)t * EMB);
#pragma unroll
        for (int e4 = 0; e4 < EMB / 4; e4++) {
            float4 wv = wr[e4];
            wih[4 * e4 + 0] = wv.x;
            wih[4 * e4 + 1] = wv.y;
            wih[4 * e4 + 2] = wv.z;
            wih[4 * e4 + 3] = wv.w;
        }
    }
    float bias = b_ih[t] + b_hh[t];

    const int len = lens[b];
    const int* ids_row = ids + (size_t)b * SEQT;
    if (t < HID) { h_sh[t] = 0.f; c_sh[t] = 0.f; }
    __syncthreads();

    for (int step = 0; step < len; step++) {
        int id = ids_row[step];
        if (t < EMB / 4) {
            ((float4*)x_sh)[t] = ((const float4*)(emb + (size_t)id * EMB))[t];
        }
        __syncthreads();
        float a0 = bias, a1 = 0.f, a2 = 0.f, a3 = 0.f;
#pragma unroll
        for (int e4 = 0; e4 < EMB / 4; e4++) {
            float4 xv = ((const float4*)x_sh)[e4];
            a0 += wih[4 * e4 + 0] * xv.x;
            a1 += wih[4 * e4 + 1] * xv.y;
            a2 += wih[4 * e4 + 2] * xv.z;
            a3 += wih[4 * e4 + 3] * xv.w;
        }
        float acc = (a0 + a1) + (a2 + a3);

        const float* wrow = W_hh + (size_t)t * HID;
        a0 = acc; a1 = 0.f; a2 = 0.f; a3 = 0.f;
        for (int k4 = 0; k4 < HID / 4; k4++) {
            float4 hv = ((const float4*)h_sh)[k4];
            float4 wv = ((const float4*)wrow)[k4];
            a0 += wv.x * hv.x;
            a1 += wv.y * hv.y;
            a2 += wv.z * hv.z;
            a3 += wv.w * hv.w;
        }
        gates[t] = (a0 + a1) + (a2 + a3);
        __syncthreads();

        if (t < HID) {
            float ig = sigmoidf_(gates[t]);
            float fg = sigmoidf_(gates[HID + t]);
            float gg = tanhf_(gates[2 * HID + t]);
            float og = sigmoidf_(gates[3 * HID + t]);
            float cc = fg * c_sh[t] + ig * gg;
            c_sh[t] = cc;
            h_sh[t] = og * tanhf_(cc);
        }
        __syncthreads();
    }
    if (t < HID) out[(size_t)b * HID + t] = h_sh[t];
}

extern "C" void kernel_launch(void* const* d_in, const int* in_sizes, int n_in,
                              void* d_out, int out_size, void* d_ws, size_t ws_size,
                              hipStream_t stream) {
    const int*   ids  = (const int*)d_in[0];
    const int*   lens = (const int*)d_in[1];
    const float* emb  = (const float*)d_in[2];
    const float* Wih  = (const float*)d_in[3];
    const float* Whh  = (const float*)d_in[4];
    const float* bih  = (const float*)d_in[5];
    const float* bhh  = (const float*)d_in[6];
    float* out = (float*)d_out;

    // ws layout: eproj 4 MB | wvq 384 KB | wlq 64 KB | wgq 64 KB
    const size_t ep_bytes = (size_t)VOCAB * G4 * sizeof(float);
    const size_t wv_off   = ep_bytes;
    const size_t wv_bytes = (size_t)2 * (KVH / 4) * G4 * 4 * sizeof(u32);
    const size_t wl_off   = wv_off + wv_bytes;
    const size_t wl_bytes = (size_t)2 * (KLS / 4) * G4 * 4 * sizeof(u32);
    const size_t wg_off   = wl_off + wl_bytes;
    const size_t wg_bytes = (size_t)2 * (KGH / 4) * G4 * 4 * sizeof(u32);

    if (ws_size >= wg_off + wg_bytes) {
        float* eproj = (float*)d_ws;
        u32*   wvp   = (u32*)((char*)d_ws + wv_off);
        u32*   wlp   = (u32*)((char*)d_ws + wl_off);
        u32*   wgp   = (u32*)((char*)d_ws + wg_off);
        eproj_kernel<<<VOCAB / 8, 1024, 0, stream>>>(emb, Wih, bih, bhh, eproj);
        pack_whh<<<G4, 128, 0, stream>>>(Whh, wvp, wlp, wgp);
        lstm_single_cu<<<BATCH, 512, 0, stream>>>(
            ids, lens, eproj, wvp, wlp, wgp, out);
    } else {
        lstm_fallback<<<BATCH, 1024, 0, stream>>>(
            ids, lens, emb, Wih, bih, bhh, Whh, out);
    }
}